// Round 3
// baseline (552.542 us; speedup 1.0000x reference)
//
#include <hip/hip_runtime.h>
#include <math.h>

#define C_CLS   1000
#define NCHUNK  250     // C_CLS / 4 float4 chunks per row
#define BLOCK   256     // 4 waves per block, 1 wave per row

__device__ __forceinline__ float wave_sum(float v) {
#pragma unroll
    for (int m = 32; m >= 1; m >>= 1) v += __shfl_xor(v, m, 64);
    return v;
}

__device__ __forceinline__ float wave_max(float v) {
#pragma unroll
    for (int m = 32; m >= 1; m >>= 1) v = fmaxf(v, __shfl_xor(v, m, 64));
    return v;
}

// fast reciprocal: v_rcp_f32 + one Newton step (~0.5 ulp)
__device__ __forceinline__ float frcp(float x) {
    float r = __builtin_amdgcn_rcpf(x);
    r = r * fmaf(-x, r, 2.0f);
    return r;
}

__global__ void __launch_bounds__(BLOCK)
bt_loss_kernel(const float* __restrict__ act,
               const int*   __restrict__ truth,
               const float* __restrict__ weight,
               const float* __restrict__ wsum_p,
               double*      __restrict__ accum,
               int B,
               float lab_on, float lab_off, float K_on, float K_off)
{
    const int wid  = blockIdx.x * (BLOCK >> 6) + (threadIdx.x >> 6);  // row
    const int lane = threadIdx.x & 63;
    if (wid >= B) return;

    const float4* row4 = reinterpret_cast<const float4*>(act + (size_t)wid * C_CLS);

    // ---- load row: 4 strided float4 chunks per lane (fully coalesced) ----
    float a0[16];
#pragma unroll
    for (int k = 0; k < 4; ++k) {
        const int cid = lane + 64 * k;
        float4 d;
        if (cid < NCHUNK) d = row4[cid];
        else              d = make_float4(-1e30f, -1e30f, -1e30f, -1e30f);
        a0[4*k+0] = d.x; a0[4*k+1] = d.y; a0[4*k+2] = d.z; a0[4*k+3] = d.w;
    }

    // ---- row max ----
    float m = -1e30f;
#pragma unroll
    for (int e = 0; e < 16; ++e) m = fmaxf(m, a0[e]);
    m = wave_max(m);

    // a0 = act - mu  (invalid slots stay ~ -1e30 -> exp_t underflows to 0)
#pragma unroll
    for (int e = 0; e < 16; ++e) a0[e] -= m;

    // ---- fixed-point normalization: 5 update iters + 1 final partition ----
    // exp_t(u, 1.2) = (1 - 0.2 u)^{-5}
    float s = 1.0f;
    float Z = 0.0f;
    for (int it = 0; it < 6; ++it) {
        const float t = -0.2f * s;
        float local = 0.0f;
#pragma unroll
        for (int e = 0; e < 16; ++e) {
            float v   = fmaf(t, a0[e], 1.0f);   // >= 1 (a0 <= 0)
            float inv = frcp(v);
            float i2  = inv * inv;
            float i4  = i2 * i2;
            local += i4 * inv;                  // v^{-5}
        }
        Z = wave_sum(local);
        if (it < 5) s = powf(Z, -0.2f);         // wave-uniform scalar
    }
    const float zp  = powf(Z, 0.2f);
    const float ncm = 5.0f * (zp - 1.0f);       // nc - mu

    // ---- final loss pass ----
    const float wsum  = *wsum_p;
    const float scale = (float)C_CLS / wsum;    // pos_weight = w * C / sum(w)
    const int   tl    = truth[wid];
    const float nl5_on  = -5.0f * lab_on;
    const float nl5_off = -5.0f * lab_off;
    const float inv12   = 1.0f / 1.2f;

    const float4* w4p = reinterpret_cast<const float4*>(weight);

    float local = 0.0f;
#pragma unroll
    for (int k = 0; k < 4; ++k) {
        const int cid = lane + 64 * k;
        if (cid < NCHUNK) {
            const float4 w4 = w4p[cid];
            const float wv[4] = { w4.x, w4.y, w4.z, w4.w };
#pragma unroll
            for (int j = 0; j < 4; ++j) {
                const int cls = cid * 4 + j;
                // u = act - nc = a0 - (nc - mu); v = 1 - 0.2u >= 1
                float u   = a0[4*k+j] - ncm;
                float v   = fmaf(-0.2f, u, 1.0f);
                float inv = frcp(v);            // = p^{0.2}
                float i2  = inv * inv;
                float i4  = i2 * i2;
                float p12 = i4 * i2;            // = p^{1.2} = v^{-6}
                const bool on  = (cls == tl);
                const float K   = on ? K_on   : K_off;
                const float nl5 = on ? nl5_on : nl5_off;
                float elem = fmaf(p12, inv12, fmaf(nl5, inv, K));
                local = fmaf(wv[j] * scale, elem, local);
            }
        }
    }
    const float rowloss = wave_sum(local);
    if (lane == 0) atomicAdd(accum, (double)rowloss);
}

__global__ void wsum_kernel(const float* __restrict__ w, float* __restrict__ out) {
    float local = 0.0f;
    for (int i = threadIdx.x; i < C_CLS; i += BLOCK) local += w[i];
    __shared__ float sm[BLOCK / 64];
    float ws = wave_sum(local);
    if ((threadIdx.x & 63) == 0) sm[threadIdx.x >> 6] = ws;
    __syncthreads();
    if (threadIdx.x == 0) {
        float t = 0.0f;
#pragma unroll
        for (int i = 0; i < BLOCK / 64; ++i) t += sm[i];
        out[0] = t;
    }
}

__global__ void finalize_kernel(const double* __restrict__ accum,
                                float* __restrict__ out, int B) {
    out[0] = (float)(accum[0] / (double)B);
}

extern "C" void kernel_launch(void* const* d_in, const int* in_sizes, int n_in,
                              void* d_out, int out_size, void* d_ws, size_t ws_size,
                              hipStream_t stream) {
    const float* act    = (const float*)d_in[0];
    const int*   truth  = (const int*)d_in[1];
    const float* weight = (const float*)d_in[2];
    float*       out    = (float*)d_out;

    const int B = in_sizes[1];   // 32768 rows

    double* accum  = (double*)d_ws;
    float*  wsum_p = (float*)((char*)d_ws + 8);

    // zero accumulator + wsum slot (ws is poisoned 0xAA before every launch)
    hipMemsetAsync(d_ws, 0, 16, stream);

    wsum_kernel<<<1, BLOCK, 0, stream>>>(weight, wsum_p);

    // host-side double-precision label constants
    const double Cd   = (double)C_CLS;
    const double coef = 1.0 - 0.05 * Cd / (Cd - 1.0);
    const double offd = 0.05 / (Cd - 1.0);
    const double lab_on  = coef + offd;   // 0.95
    const double lab_off = offd;
    auto logt1 = [](double u) { return (pow(u, 0.2) - 1.0) / 0.2; };
    // K = lab*log_t(lab+1e-10) - lab^{1.2}/1.2 + 5*lab
    const double K_on  = lab_on  * logt1(lab_on  + 1e-10) - pow(lab_on,  1.2) / 1.2 + 5.0 * lab_on;
    const double K_off = lab_off * logt1(lab_off + 1e-10) - pow(lab_off, 1.2) / 1.2 + 5.0 * lab_off;

    const int blocks = (B + 3) / 4;  // 4 rows (waves) per block
    bt_loss_kernel<<<blocks, BLOCK, 0, stream>>>(
        act, truth, weight, wsum_p, accum, B,
        (float)lab_on, (float)lab_off, (float)K_on, (float)K_off);

    finalize_kernel<<<1, 1, 0, stream>>>(accum, out, B);
}

// Round 6
// 204.916 us; speedup vs baseline: 2.6964x; 2.6964x over previous
//
#include <hip/hip_runtime.h>
#include <math.h>

#define C_CLS   1000
#define NCHUNK  250     // C_CLS / 4 float4 chunks per row
#define BLOCK   256     // 4 waves per block, 1 wave per row
#define RBLOCK  1024    // reduction block

__device__ __forceinline__ float wave_sum(float v) {
#pragma unroll
    for (int m = 32; m >= 1; m >>= 1) v += __shfl_xor(v, m, 64);
    return v;
}

__device__ __forceinline__ float wave_max(float v) {
#pragma unroll
    for (int m = 32; m >= 1; m >>= 1) v = fmaxf(v, __shfl_xor(v, m, 64));
    return v;
}

// raw v_rcp_f32 (~1 ulp). Raised to 5th/6th power -> ~1e-6 rel error,
// vs 5.8e-2 abs threshold on a mean of 32768 rows: ample margin.
__device__ __forceinline__ float frcp(float x) {
    return __builtin_amdgcn_rcpf(x);
}

// x^p via v_exp_f32/v_log_f32 (x >= 1 here, p in [-0.2, 0.2])
__device__ __forceinline__ float fpow(float x, float p) {
    return __builtin_amdgcn_exp2f(p * __builtin_amdgcn_logf(x));
}

__global__ void __launch_bounds__(BLOCK)
bt_loss_kernel(const float* __restrict__ act,
               const int*   __restrict__ truth,
               const float* __restrict__ weight,
               float*       __restrict__ partials,
               int B,
               float lab_on, float lab_off, float K_on, float K_off)
{
    const int wid  = blockIdx.x * (BLOCK >> 6) + (threadIdx.x >> 6);  // row
    const int lane = threadIdx.x & 63;
    if (wid >= B) return;

    const float4* row4 = reinterpret_cast<const float4*>(act + (size_t)wid * C_CLS);

    // ---- load row: 4 strided float4 chunks per lane (fully coalesced) ----
    float a0[16];
#pragma unroll
    for (int k = 0; k < 4; ++k) {
        const int cid = lane + 64 * k;
        float4 d;
        if (cid < NCHUNK) d = row4[cid];
        else              d = make_float4(-1e30f, -1e30f, -1e30f, -1e30f);
        a0[4*k+0] = d.x; a0[4*k+1] = d.y; a0[4*k+2] = d.z; a0[4*k+3] = d.w;
    }

    // ---- row max ----
    float m = -1e30f;
#pragma unroll
    for (int e = 0; e < 16; ++e) m = fmaxf(m, a0[e]);
    m = wave_max(m);

    // a0 = act - mu  (invalid slots stay ~ -1e30 -> exp_t underflows to 0)
#pragma unroll
    for (int e = 0; e < 16; ++e) a0[e] -= m;

    // ---- fixed-point normalization: 5 update iters + 1 final partition ----
    // exp_t(u, 1.2) = (1 - 0.2 u)^{-5}
    float s = 1.0f;
    float Z = 0.0f;
    for (int it = 0; it < 6; ++it) {
        const float t = -0.2f * s;
        float local = 0.0f;
#pragma unroll
        for (int e = 0; e < 16; ++e) {
            float v   = fmaf(t, a0[e], 1.0f);   // >= 1 (a0 <= 0)
            float inv = frcp(v);
            float i2  = inv * inv;
            float i4  = i2 * i2;
            local += i4 * inv;                  // v^{-5}
        }
        Z = wave_sum(local);
        if (it < 5) s = fpow(Z, -0.2f);         // wave-uniform scalar
    }
    const float ncm = 5.0f * (fpow(Z, 0.2f) - 1.0f);   // nc - mu

    // ---- final loss pass (unscaled; global C/wsum factor applied at reduce) ----
    const int   tl      = truth[wid];
    const float nl5_on  = -5.0f * lab_on;
    const float nl5_off = -5.0f * lab_off;
    const float inv12   = 1.0f / 1.2f;

    const float4* w4p = reinterpret_cast<const float4*>(weight);

    float local = 0.0f;
#pragma unroll
    for (int k = 0; k < 4; ++k) {
        const int cid = lane + 64 * k;
        if (cid < NCHUNK) {
            const float4 w4 = w4p[cid];
            const float wv[4] = { w4.x, w4.y, w4.z, w4.w };
#pragma unroll
            for (int j = 0; j < 4; ++j) {
                const int cls = cid * 4 + j;
                // u = act - nc = a0 - (nc - mu); v = 1 - 0.2u >= 1
                float u   = a0[4*k+j] - ncm;
                float v   = fmaf(-0.2f, u, 1.0f);
                float inv = frcp(v);            // = p^{0.2}
                float i2  = inv * inv;
                float i4  = i2 * i2;
                float p12 = i4 * i2;            // = p^{1.2} = v^{-6}
                const bool on  = (cls == tl);
                const float K   = on ? K_on   : K_off;
                const float nl5 = on ? nl5_on : nl5_off;
                float elem = fmaf(p12, inv12, fmaf(nl5, inv, K));
                local = fmaf(wv[j], elem, local);
            }
        }
    }
    const float rowloss = wave_sum(local);
    if (lane == 0) partials[wid] = rowloss;     // plain store, no atomics
}

__global__ void __launch_bounds__(RBLOCK)
reduce_kernel(const float* __restrict__ partials,
              const float* __restrict__ weight,
              float* __restrict__ out, int B)
{
    double acc  = 0.0;
    for (int i = threadIdx.x; i < B; i += RBLOCK) acc += (double)partials[i];
    double wacc = 0.0;
    for (int i = threadIdx.x; i < C_CLS; i += RBLOCK) wacc += (double)weight[i];

#pragma unroll
    for (int m = 32; m >= 1; m >>= 1) {
        acc  += __shfl_xor(acc,  m, 64);
        wacc += __shfl_xor(wacc, m, 64);
    }

    __shared__ double sm[RBLOCK / 64], sw[RBLOCK / 64];
    const int w = threadIdx.x >> 6;
    if ((threadIdx.x & 63) == 0) { sm[w] = acc; sw[w] = wacc; }
    __syncthreads();
    if (threadIdx.x == 0) {
        double t = 0.0, tw = 0.0;
#pragma unroll
        for (int i = 0; i < RBLOCK / 64; ++i) { t += sm[i]; tw += sw[i]; }
        // mean over B of (C/wsum) * row_total
        out[0] = (float)(t * ((double)C_CLS / tw) / (double)B);
    }
}

extern "C" void kernel_launch(void* const* d_in, const int* in_sizes, int n_in,
                              void* d_out, int out_size, void* d_ws, size_t ws_size,
                              hipStream_t stream) {
    const float* act    = (const float*)d_in[0];
    const int*   truth  = (const int*)d_in[1];
    const float* weight = (const float*)d_in[2];
    float*       out    = (float*)d_out;

    const int B = in_sizes[1];   // 32768 rows

    float* partials = (float*)d_ws;   // B floats (written for every row each call)

    // host-side double-precision label constants
    const double Cd   = (double)C_CLS;
    const double coef = 1.0 - 0.05 * Cd / (Cd - 1.0);
    const double offd = 0.05 / (Cd - 1.0);
    const double lab_on  = coef + offd;   // 0.95
    const double lab_off = offd;
    auto logt1 = [](double u) { return (pow(u, 0.2) - 1.0) / 0.2; };
    // K = lab*log_t(lab+1e-10) - lab^{1.2}/1.2 + 5*lab
    const double K_on  = lab_on  * logt1(lab_on  + 1e-10) - pow(lab_on,  1.2) / 1.2 + 5.0 * lab_on;
    const double K_off = lab_off * logt1(lab_off + 1e-10) - pow(lab_off, 1.2) / 1.2 + 5.0 * lab_off;

    const int blocks = (B + 3) / 4;  // 4 rows (waves) per block
    bt_loss_kernel<<<blocks, BLOCK, 0, stream>>>(
        act, truth, weight, partials, B,
        (float)lab_on, (float)lab_off, (float)K_on, (float)K_off);

    reduce_kernel<<<1, RBLOCK, 0, stream>>>(partials, weight, out, B);
}

// Round 7
// 202.780 us; speedup vs baseline: 2.7248x; 1.0105x over previous
//
#include <hip/hip_runtime.h>
#include <math.h>

#define C_CLS   1000
#define NCHUNK  250     // C_CLS / 4 float4 chunks per row
#define BLOCK   256     // 4 waves per block, 1 wave per row
#define RBLOCK  256     // reduction block

__device__ __forceinline__ float wave_sum(float v) {
#pragma unroll
    for (int m = 32; m >= 1; m >>= 1) v += __shfl_xor(v, m, 64);
    return v;
}

__device__ __forceinline__ float wave_max(float v) {
#pragma unroll
    for (int m = 32; m >= 1; m >>= 1) v = fmaxf(v, __shfl_xor(v, m, 64));
    return v;
}

// raw v_rcp_f32 (~1 ulp). Raised to 5th/6th power -> ~1e-6 rel error,
// vs 5.8e-2 abs threshold on a mean of 32768 rows: ample margin.
__device__ __forceinline__ float frcp(float x) {
    return __builtin_amdgcn_rcpf(x);
}

// x^p via v_exp_f32/v_log_f32 (x >= 1 here, p in [-0.2, 0.2])
__device__ __forceinline__ float fpow(float x, float p) {
    return __builtin_amdgcn_exp2f(p * __builtin_amdgcn_logf(x));
}

__global__ void __launch_bounds__(BLOCK)
bt_loss_kernel(const float* __restrict__ act,
               const int*   __restrict__ truth,
               const float* __restrict__ weight,
               float*       __restrict__ partials,   // one per BLOCK (4 rows)
               int B,
               float lab_on, float lab_off, float K_on, float K_off)
{
    const int wid  = blockIdx.x * (BLOCK >> 6) + (threadIdx.x >> 6);  // row
    const int lane = threadIdx.x & 63;
    const int warp = threadIdx.x >> 6;

    float rowloss = 0.0f;
    if (wid < B) {
        const float4* row4 = reinterpret_cast<const float4*>(act + (size_t)wid * C_CLS);

        // ---- load row: 4 strided float4 chunks per lane (fully coalesced) ----
        float a0[16];
#pragma unroll
        for (int k = 0; k < 4; ++k) {
            const int cid = lane + 64 * k;
            float4 d;
            if (cid < NCHUNK) d = row4[cid];
            else              d = make_float4(-1e30f, -1e30f, -1e30f, -1e30f);
            a0[4*k+0] = d.x; a0[4*k+1] = d.y; a0[4*k+2] = d.z; a0[4*k+3] = d.w;
        }

        // ---- row max ----
        float m = -1e30f;
#pragma unroll
        for (int e = 0; e < 16; ++e) m = fmaxf(m, a0[e]);
        m = wave_max(m);

        // a0 = act - mu  (invalid slots stay ~ -1e30 -> exp_t underflows to 0)
#pragma unroll
        for (int e = 0; e < 16; ++e) a0[e] -= m;

        // ---- fixed-point normalization: 5 update iters + 1 final partition ----
        // exp_t(u, 1.2) = (1 - 0.2 u)^{-5}
        float s = 1.0f;
        float Z = 0.0f;
        for (int it = 0; it < 6; ++it) {
            const float t = -0.2f * s;
            float local = 0.0f;
#pragma unroll
            for (int e = 0; e < 16; ++e) {
                float v   = fmaf(t, a0[e], 1.0f);   // >= 1 (a0 <= 0)
                float inv = frcp(v);
                float i2  = inv * inv;
                float i4  = i2 * i2;
                local = fmaf(i4, inv, local);       // += v^{-5}
            }
            Z = wave_sum(local);
            if (it < 5) s = fpow(Z, -0.2f);         // wave-uniform scalar
        }
        const float ncm   = 5.0f * (fpow(Z, 0.2f) - 1.0f);  // nc - mu
        const float vbase = fmaf(0.2f, ncm, 1.0f);          // 1 + 0.2*ncm

        // ---- final loss pass (unscaled; global C/wsum factor at reduce) ----
        // v = 1 - 0.2(a0 - ncm) = vbase - 0.2*a0   (one fma per element)
        const int   tl      = truth[wid];
        const float nl5_on  = -5.0f * lab_on;
        const float nl5_off = -5.0f * lab_off;
        const float inv12   = 1.0f / 1.2f;

        const float4* w4p = reinterpret_cast<const float4*>(weight);

        float local = 0.0f;
#pragma unroll
        for (int k = 0; k < 4; ++k) {
            const int cid = lane + 64 * k;
            if (cid < NCHUNK) {
                const float4 w4 = w4p[cid];
                const float wv[4] = { w4.x, w4.y, w4.z, w4.w };
#pragma unroll
                for (int j = 0; j < 4; ++j) {
                    const int cls = cid * 4 + j;
                    float v   = fmaf(-0.2f, a0[4*k+j], vbase);
                    float inv = frcp(v);            // = p^{0.2}
                    float i2  = inv * inv;
                    float i4  = i2 * i2;
                    float p12 = i4 * i2;            // = p^{1.2} = v^{-6}
                    const bool on  = (cls == tl);
                    const float K   = on ? K_on   : K_off;
                    const float nl5 = on ? nl5_on : nl5_off;
                    float elem = fmaf(p12, inv12, fmaf(nl5, inv, K));
                    local = fmaf(wv[j], elem, local);
                }
            }
        }
        rowloss = wave_sum(local);
    }

    // ---- block-level partial: 4 rows -> 1 float ----
    __shared__ float smrow[BLOCK / 64];
    if (lane == 0) smrow[warp] = rowloss;
    __syncthreads();
    if (threadIdx.x == 0)
        partials[blockIdx.x] = smrow[0] + smrow[1] + smrow[2] + smrow[3];
}

__global__ void __launch_bounds__(RBLOCK)
reduce_kernel(const float* __restrict__ partials,
              const float* __restrict__ weight,
              float* __restrict__ out, int n, int B)
{
    double acc = 0.0;
    for (int i = threadIdx.x; i < n; i += RBLOCK) acc += (double)partials[i];
    double wacc = 0.0;
    for (int i = threadIdx.x; i < C_CLS; i += RBLOCK) wacc += (double)weight[i];

#pragma unroll
    for (int m = 32; m >= 1; m >>= 1) {
        acc  += __shfl_xor(acc,  m, 64);
        wacc += __shfl_xor(wacc, m, 64);
    }

    __shared__ double sm[RBLOCK / 64], sw[RBLOCK / 64];
    const int w = threadIdx.x >> 6;
    if ((threadIdx.x & 63) == 0) { sm[w] = acc; sw[w] = wacc; }
    __syncthreads();
    if (threadIdx.x == 0) {
        double t = 0.0, tw = 0.0;
#pragma unroll
        for (int i = 0; i < RBLOCK / 64; ++i) { t += sm[i]; tw += sw[i]; }
        // mean over B of (C/wsum) * row_total
        out[0] = (float)(t * ((double)C_CLS / tw) / (double)B);
    }
}

extern "C" void kernel_launch(void* const* d_in, const int* in_sizes, int n_in,
                              void* d_out, int out_size, void* d_ws, size_t ws_size,
                              hipStream_t stream) {
    const float* act    = (const float*)d_in[0];
    const int*   truth  = (const int*)d_in[1];
    const float* weight = (const float*)d_in[2];
    float*       out    = (float*)d_out;

    const int B = in_sizes[1];   // 32768 rows

    float* partials = (float*)d_ws;   // one float per block

    // host-side double-precision label constants
    const double Cd   = (double)C_CLS;
    const double coef = 1.0 - 0.05 * Cd / (Cd - 1.0);
    const double offd = 0.05 / (Cd - 1.0);
    const double lab_on  = coef + offd;   // 0.95
    const double lab_off = offd;
    auto logt1 = [](double u) { return (pow(u, 0.2) - 1.0) / 0.2; };
    // K = lab*log_t(lab+1e-10) - lab^{1.2}/1.2 + 5*lab
    const double K_on  = lab_on  * logt1(lab_on  + 1e-10) - pow(lab_on,  1.2) / 1.2 + 5.0 * lab_on;
    const double K_off = lab_off * logt1(lab_off + 1e-10) - pow(lab_off, 1.2) / 1.2 + 5.0 * lab_off;

    const int blocks = (B + 3) / 4;  // 4 rows (waves) per block
    bt_loss_kernel<<<blocks, BLOCK, 0, stream>>>(
        act, truth, weight, partials, B,
        (float)lab_on, (float)lab_off, (float)K_on, (float)K_off);

    reduce_kernel<<<1, RBLOCK, 0, stream>>>(partials, weight, out, blocks, B);
}

// Round 8
// 200.488 us; speedup vs baseline: 2.7560x; 1.0114x over previous
//
#include <hip/hip_runtime.h>
#include <math.h>

#define C_CLS   1000
#define NCHUNK  250     // C_CLS / 4 float4 chunks per row
#define BLOCK   256     // 4 waves per block, 1 wave per row
#define RBLOCK  256     // reduction block

__device__ __forceinline__ float wave_sum(float v) {
#pragma unroll
    for (int m = 32; m >= 1; m >>= 1) v += __shfl_xor(v, m, 64);
    return v;
}

__device__ __forceinline__ float wave_max(float v) {
#pragma unroll
    for (int m = 32; m >= 1; m >>= 1) v = fmaxf(v, __shfl_xor(v, m, 64));
    return v;
}

// raw v_rcp_f32 (~1 ulp). Raised to 5th/6th power -> ~1e-6 rel error,
// vs 5.8e-2 abs threshold on a mean of 32768 rows: ample margin.
__device__ __forceinline__ float frcp(float x) {
    return __builtin_amdgcn_rcpf(x);
}

// x^p via v_exp_f32/v_log_f32 (x >= 1 here, p in [-0.2, 0.2])
__device__ __forceinline__ float fpow(float x, float p) {
    return __builtin_amdgcn_exp2f(p * __builtin_amdgcn_logf(x));
}

__global__ void __launch_bounds__(BLOCK)
bt_loss_kernel(const float* __restrict__ act,
               const int*   __restrict__ truth,
               const float* __restrict__ weight,
               float*       __restrict__ partials,   // one per BLOCK (4 rows)
               int B,
               float nl5_off, float dnl5, float dK)
{
    const int wid  = blockIdx.x * (BLOCK >> 6) + (threadIdx.x >> 6);  // row
    const int lane = threadIdx.x & 63;
    const int warp = threadIdx.x >> 6;

    float rowloss = 0.0f;
    if (wid < B) {
        const size_t rbase = (size_t)wid * C_CLS;
        const float4* row4 = reinterpret_cast<const float4*>(act + rbase);

        // ---- early uniform loads: latency hides under the iteration loop ----
        const int   tl   = truth[wid];
        const float a_tl = act[rbase + (size_t)tl];
        const float w_tl = weight[tl];

        // ---- load row: 4 strided float4 chunks per lane (fully coalesced) ----
        float a[16];
#pragma unroll
        for (int k = 0; k < 4; ++k) {
            const int cid = lane + 64 * k;
            float4 d;
            if (cid < NCHUNK) d = row4[cid];
            else              d = make_float4(-1e30f, -1e30f, -1e30f, -1e30f);
            a[4*k+0] = d.x; a[4*k+1] = d.y; a[4*k+2] = d.z; a[4*k+3] = d.w;
        }

        // ---- row max (raw logits; mu folded into per-iter scalar base) ----
        float mu = -1e30f;
#pragma unroll
        for (int e = 0; e < 16; ++e) mu = fmaxf(mu, a[e]);
        mu = wave_max(mu);

        // ---- fixed-point normalization: 5 update iters + 1 final partition ----
        // exp_t(u,1.2) = (1-0.2u)^{-5};  v = 1 - 0.2*s*(a-mu) = base + c*a,
        // c = -0.2*s, base = 1 + 0.2*s*mu.  Padding a=-1e30 -> v huge -> term 0.
        float s = 1.0f;
        float Z = 0.0f;
        for (int it = 0; it < 6; ++it) {
            const float c    = -0.2f * s;
            const float base = fmaf(0.2f * s, mu, 1.0f);
            float local = 0.0f;
#pragma unroll
            for (int e = 0; e < 16; ++e) {
                float v   = fmaf(c, a[e], base);    // >= 1
                float inv = frcp(v);
                float i2  = inv * inv;
                float i4  = i2 * i2;
                local = fmaf(i4, inv, local);       // += v^{-5}
            }
            Z = wave_sum(local);
            if (it < 5) s = fpow(Z, -0.2f);         // wave-uniform scalar
        }
        const float ncm = 5.0f * (fpow(Z, 0.2f) - 1.0f);  // nc - mu
        const float vb  = fmaf(0.2f, ncm + mu, 1.0f);     // v = vb - 0.2*a_raw

        // ---- final pass: S1 = sum w*p^{1.2}, S2 = sum w*p^{0.2} ----
        const float4* w4p = reinterpret_cast<const float4*>(weight);
        float S1 = 0.0f, S2 = 0.0f;
#pragma unroll
        for (int k = 0; k < 4; ++k) {
            const int cid = lane + 64 * k;
            if (cid < NCHUNK) {
                const float4 w4 = w4p[cid];
                const float wv[4] = { w4.x, w4.y, w4.z, w4.w };
#pragma unroll
                for (int j = 0; j < 4; ++j) {
                    float v   = fmaf(-0.2f, a[4*k+j], vb);
                    float inv = frcp(v);            // = p^{0.2}
                    float i2  = inv * inv;
                    float i4  = i2 * i2;
                    float p12 = i4 * i2;            // = p^{1.2}
                    S1 = fmaf(wv[j], p12, S1);
                    S2 = fmaf(wv[j], inv, S2);
                }
            }
        }
        S1 = wave_sum(S1);
        S2 = wave_sum(S2);

        // true-label correction (wave-uniform, loads hoisted above)
        const float inv_tl = frcp(fmaf(-0.2f, a_tl, vb));
        rowloss = fmaf(S1, (1.0f / 1.2f), nl5_off * S2)
                + w_tl * fmaf(dnl5, inv_tl, dK);
    }

    // ---- block-level partial: 4 rows -> 1 float ----
    __shared__ float smrow[BLOCK / 64];
    if (lane == 0) smrow[warp] = rowloss;
    __syncthreads();
    if (threadIdx.x == 0)
        partials[blockIdx.x] = smrow[0] + smrow[1] + smrow[2] + smrow[3];
}

__global__ void __launch_bounds__(RBLOCK)
reduce_kernel(const float* __restrict__ partials,
              const float* __restrict__ weight,
              float* __restrict__ out, int n, int B, double CKoff)
{
    double acc = 0.0;
    for (int i = threadIdx.x; i < n; i += RBLOCK) acc += (double)partials[i];
    double wacc = 0.0;
    for (int i = threadIdx.x; i < C_CLS; i += RBLOCK) wacc += (double)weight[i];

#pragma unroll
    for (int m = 32; m >= 1; m >>= 1) {
        acc  += __shfl_xor(acc,  m, 64);
        wacc += __shfl_xor(wacc, m, 64);
    }

    __shared__ double sm[RBLOCK / 64], sw[RBLOCK / 64];
    const int w = threadIdx.x >> 6;
    if ((threadIdx.x & 63) == 0) { sm[w] = acc; sw[w] = wacc; }
    __syncthreads();
    if (threadIdx.x == 0) {
        double t = 0.0, tw = 0.0;
#pragma unroll
        for (int i = 0; i < RBLOCK / 64; ++i) { t += sm[i]; tw += sw[i]; }
        // mean = (C/wsum) * (sum of per-row partials)/B + C*K_off
        out[0] = (float)(((double)C_CLS / tw) * (t / (double)B) + CKoff);
    }
}

extern "C" void kernel_launch(void* const* d_in, const int* in_sizes, int n_in,
                              void* d_out, int out_size, void* d_ws, size_t ws_size,
                              hipStream_t stream) {
    const float* act    = (const float*)d_in[0];
    const int*   truth  = (const int*)d_in[1];
    const float* weight = (const float*)d_in[2];
    float*       out    = (float*)d_out;

    const int B = in_sizes[1];   // 32768 rows

    float* partials = (float*)d_ws;   // one float per block

    // host-side double-precision label constants
    const double Cd   = (double)C_CLS;
    const double coef = 1.0 - 0.05 * Cd / (Cd - 1.0);
    const double offd = 0.05 / (Cd - 1.0);
    const double lab_on  = coef + offd;   // 0.95
    const double lab_off = offd;
    auto logt1 = [](double u) { return (pow(u, 0.2) - 1.0) / 0.2; };
    // K = lab*log_t(lab+1e-10) - lab^{1.2}/1.2 + 5*lab
    const double K_on  = lab_on  * logt1(lab_on  + 1e-10) - pow(lab_on,  1.2) / 1.2 + 5.0 * lab_on;
    const double K_off = lab_off * logt1(lab_off + 1e-10) - pow(lab_off, 1.2) / 1.2 + 5.0 * lab_off;
    const double nl5_on  = -5.0 * lab_on;
    const double nl5_off = -5.0 * lab_off;

    const int blocks = (B + 3) / 4;  // 4 rows (waves) per block
    bt_loss_kernel<<<blocks, BLOCK, 0, stream>>>(
        act, truth, weight, partials, B,
        (float)nl5_off, (float)(nl5_on - nl5_off), (float)(K_on - K_off));

    reduce_kernel<<<1, RBLOCK, 0, stream>>>(partials, weight, out, blocks, B,
                                            Cd * K_off);
}